// Round 1
// baseline (238.824 us; speedup 1.0000x reference)
//
#include <hip/hip_runtime.h>
#include <hip/hip_bf16.h>
#include <math.h>

// Problem dims (fixed): B=4, H=W=64, DIM=512, HEADS=64, QKV=8
// NPOS = B*H*W = 16384 positions, 4096 per batch.
// qs[b,h,w] = x[b,h,w,:] . wq_sum   (wq_sum[c] = sum_{n,p} w_q[c,n,p])
// ks likewise. weights[...,p,q] = softmax_q(qs*ks[b,p,q]*SCALE)
// attn[b,h,w,p,d] = sum_q weights * v[b,h,w,q,d],  v = x @ w_v.

#define SCALE 0.35355339059327373f  // 8^-0.5

// ---------------- tiny: column sums of w_q / w_k ----------------
// 1024 waves: wave g<512 -> wq_sum[g], else wk_sum[g-512]
__global__ __launch_bounds__(256) void k_wsum(const float* __restrict__ wq,
                                              const float* __restrict__ wk,
                                              float* __restrict__ wqs,
                                              float* __restrict__ wks) {
    int gw = blockIdx.x * 4 + (threadIdx.x >> 6);  // 0..1023
    int lane = threadIdx.x & 63;
    const float* src = (gw < 512) ? wq : wk;
    int c = gw & 511;
    const float4* row = (const float4*)(src + (size_t)c * 512);
    float4 a = row[lane * 2], b = row[lane * 2 + 1];
    float s = a.x + a.y + a.z + a.w + b.x + b.y + b.z + b.w;
#pragma unroll
    for (int off = 32; off; off >>= 1) s += __shfl_xor(s, off);
    if (lane == 0) {
        if (gw < 512) wqs[c] = s; else wks[c] = s;
    }
}

// ---------------- qs / ks: one wave per position ----------------
__global__ __launch_bounds__(256) void k_qsks(const float* __restrict__ x,
                                              const float* __restrict__ wqs,
                                              const float* __restrict__ wks,
                                              float* __restrict__ qs,
                                              float* __restrict__ ks) {
    int row = blockIdx.x * 4 + (threadIdx.x >> 6);  // 0..16383
    int lane = threadIdx.x & 63;
    const float4* xr = (const float4*)(x + (size_t)row * 512);
    const float4* q4 = (const float4*)wqs;
    const float4* k4 = (const float4*)wks;
    float sq = 0.f, sk = 0.f;
#pragma unroll
    for (int i = 0; i < 2; ++i) {
        float4 xv = xr[lane * 2 + i];
        float4 qv = q4[lane * 2 + i];
        float4 kv = k4[lane * 2 + i];
        sq += xv.x * qv.x + xv.y * qv.y + xv.z * qv.z + xv.w * qv.w;
        sk += xv.x * kv.x + xv.y * kv.y + xv.z * kv.z + xv.w * kv.w;
    }
#pragma unroll
    for (int off = 32; off; off >>= 1) {
        sq += __shfl_xor(sq, off);
        sk += __shfl_xor(sk, off);
    }
    if (lane == 0) { qs[row] = sq; ks[row] = sk; }
}

// ---------------- per-(b,p) row max/min of ks ----------------
__global__ __launch_bounds__(64) void k_minmax(const float* __restrict__ ks,
                                               float* __restrict__ kmax,
                                               float* __restrict__ kmin) {
    int bp = blockIdx.x;          // b*64 + p, 0..255
    int lane = threadIdx.x;       // q
    float v = ks[bp * 64 + lane];
    float hi = v, lo = v;
#pragma unroll
    for (int off = 32; off; off >>= 1) {
        hi = fmaxf(hi, __shfl_xor(hi, off));
        lo = fminf(lo, __shfl_xor(lo, off));
    }
    if (lane == 0) { kmax[bp] = hi; kmin[bp] = lo; }
}

// ---------------- fused: V projection + softmax-weighted sum ----------------
// One block handles 16 consecutive positions (all same batch b).
// LDS: xs[16][512] (x rows), vs[16][512] (V rows) = 64 KB.
__global__ __launch_bounds__(256) void k_main(const float* __restrict__ x,
                                              const float* __restrict__ wv,
                                              const float* __restrict__ qs,
                                              const float* __restrict__ ks,
                                              const float* __restrict__ kmax,
                                              const float* __restrict__ kmin,
                                              float* __restrict__ out) {
    __shared__ float xs[16 * 512];
    __shared__ float vs[16 * 512];
    const int tid = threadIdx.x;
    const int r0 = blockIdx.x * 16;   // first position index
    const int b = r0 >> 12;           // 4096 positions per batch

    // phase 1: stage 16 x-rows (coalesced float4)
    {
        const float4* xg = (const float4*)(x + (size_t)r0 * 512);
        float4* s4 = (float4*)xs;
#pragma unroll
        for (int i = 0; i < 8; ++i) s4[tid + 256 * i] = xg[tid + 256 * i];
    }
    __syncthreads();

    // phase 2: V[16][512] = X[16][512] @ Wv[512][512]; thread owns columns n0,n0+1
    const int n0 = tid * 2;
    float acc0[16], acc1[16];
#pragma unroll
    for (int m = 0; m < 16; ++m) { acc0[m] = 0.f; acc1[m] = 0.f; }
    for (int k = 0; k < 512; k += 4) {
        float2 w0 = *(const float2*)(wv + (size_t)(k + 0) * 512 + n0);
        float2 w1 = *(const float2*)(wv + (size_t)(k + 1) * 512 + n0);
        float2 w2 = *(const float2*)(wv + (size_t)(k + 2) * 512 + n0);
        float2 w3 = *(const float2*)(wv + (size_t)(k + 3) * 512 + n0);
#pragma unroll
        for (int m = 0; m < 16; ++m) {
            float4 xv = *(const float4*)(&xs[m * 512 + k]);
            acc0[m] = fmaf(xv.x, w0.x, fmaf(xv.y, w1.x, fmaf(xv.z, w2.x, fmaf(xv.w, w3.x, acc0[m]))));
            acc1[m] = fmaf(xv.x, w0.y, fmaf(xv.y, w1.y, fmaf(xv.z, w2.y, fmaf(xv.w, w3.y, acc1[m]))));
        }
    }
#pragma unroll
    for (int m = 0; m < 16; ++m) {
        *(float2*)(&vs[m * 512 + n0]) = make_float2(acc0[m], acc1[m]);
    }
    __syncthreads();

    // phase 3: softmax over q + weighted sum of V.
    // Quad of threads per p-row; sub-lane handles q = sub + 4*i (stride-4 ->
    // the 4 sub-lanes hit 4 distinct LDS bank-quads: conflict-free b128 reads).
    const int p = tid >> 2, sub = tid & 3;
    const float khi = kmax[b * 64 + p];
    const float klo = kmin[b * 64 + p];
    const float* krow = ks + b * 4096 + p * 64;
    float kv[16];
#pragma unroll
    for (int i = 0; i < 16; ++i) kv[i] = krow[sub + 4 * i];
    const size_t obase = (size_t)r0 * 512 + (size_t)p * 8;

    for (int m = 0; m < 16; ++m) {
        float s = qs[r0 + m] * SCALE;
        float rmax = (s >= 0.f) ? s * khi : s * klo;  // exact row max (monotone)
        float den = 0.f;
        float a0 = 0, a1 = 0, a2 = 0, a3 = 0, a4 = 0, a5 = 0, a6 = 0, a7 = 0;
#pragma unroll
        for (int i = 0; i < 16; ++i) {
            float e = __expf(fmaf(s, kv[i], -rmax));  // <= 0 -> no overflow
            den += e;
            const float4* vr = (const float4*)(&vs[m * 512 + (sub + 4 * i) * 8]);
            float4 v0 = vr[0], v1 = vr[1];
            a0 = fmaf(e, v0.x, a0); a1 = fmaf(e, v0.y, a1);
            a2 = fmaf(e, v0.z, a2); a3 = fmaf(e, v0.w, a3);
            a4 = fmaf(e, v1.x, a4); a5 = fmaf(e, v1.y, a5);
            a6 = fmaf(e, v1.z, a6); a7 = fmaf(e, v1.w, a7);
        }
        // reduce across the quad (lanes differ in bits 0..1 only)
#pragma unroll
        for (int off = 1; off <= 2; off <<= 1) {
            den += __shfl_xor(den, off);
            a0 += __shfl_xor(a0, off); a1 += __shfl_xor(a1, off);
            a2 += __shfl_xor(a2, off); a3 += __shfl_xor(a3, off);
            a4 += __shfl_xor(a4, off); a5 += __shfl_xor(a5, off);
            a6 += __shfl_xor(a6, off); a7 += __shfl_xor(a7, off);
        }
        if (sub == 0) {
            float inv = 1.0f / den;
            float4* o4 = (float4*)(out + obase + (size_t)m * 512);
            o4[0] = make_float4(a0 * inv, a1 * inv, a2 * inv, a3 * inv);
            o4[1] = make_float4(a4 * inv, a5 * inv, a6 * inv, a7 * inv);
        }
    }
}

extern "C" void kernel_launch(void* const* d_in, const int* in_sizes, int n_in,
                              void* d_out, int out_size, void* d_ws, size_t ws_size,
                              hipStream_t stream) {
    const float* x  = (const float*)d_in[0];
    const float* wq = (const float*)d_in[1];
    const float* wk = (const float*)d_in[2];
    const float* wv = (const float*)d_in[3];
    float* out = (float*)d_out;

    float* ws   = (float*)d_ws;
    float* qs   = ws;            // 16384
    float* ks   = ws + 16384;    // 16384
    float* wqs  = ws + 32768;    // 512
    float* wks  = ws + 33280;    // 512
    float* kmax = ws + 33792;    // 256
    float* kmin = ws + 34048;    // 256

    hipLaunchKernelGGL(k_wsum,   dim3(256),  dim3(256), 0, stream, wq, wk, wqs, wks);
    hipLaunchKernelGGL(k_qsks,   dim3(4096), dim3(256), 0, stream, x, wqs, wks, qs, ks);
    hipLaunchKernelGGL(k_minmax, dim3(256),  dim3(64),  0, stream, ks, kmax, kmin);
    hipLaunchKernelGGL(k_main,   dim3(1024), dim3(256), 0, stream, x, wv, qs, ks, kmax, kmin, out);
}